// Round 5
// baseline (1064.357 us; speedup 1.0000x reference)
//
#include <hip/hip_runtime.h>
#include <hip/hip_cooperative_groups.h>
#include <stdint.h>

#pragma clang fp contract(off)

typedef unsigned long long u64;

#define FH 512
#define FW 512
#define NA 9
#define HW (FH*FW)
#define TOTAL (HW*NA)
#define PRE_NMS 12000
#define POST_NMS 2000
#define NMS_WORDS 188            // ceil(12000/64)
#define MROW 192                 // padded words per mask row (1536 B)
#define MROWS_ALLOC 12032        // rows allocated (diag preloads read up to 12031)
#define CAND_MAX 16384
#define NMS_TH 0.7f
#define MIN_SIZE_C 16.0f
#define NBLK 512
#define NTHR 256
#define GSIZE (NBLK*NTHR)        // 131072

// generate_anchors(16, (0.5,1,2), (8,16,32)) — classic py-faster-rcnn table
__constant__ float ANCH[NA][4] = {
  {-84.f,-40.f,99.f,55.f},
  {-176.f,-88.f,191.f,103.f},
  {-360.f,-184.f,375.f,199.f},
  {-56.f,-56.f,71.f,71.f},
  {-120.f,-120.f,135.f,135.f},
  {-248.f,-248.f,263.f,263.f},
  {-36.f,-80.f,51.f,95.f},
  {-80.f,-168.f,95.f,183.f},
  {-168.f,-344.f,183.f,359.f}
};

__device__ __forceinline__ void decode_box(int a, int h, int w,
    const float* __restrict__ deltas, float im_h, float im_w,
    float& x1, float& y1, float& x2, float& y2) {
  float sx = (float)(w * 16);
  float sy = (float)(h * 16);
  float ax1 = ANCH[a][0] + sx;
  float ay1 = ANCH[a][1] + sy;
  float ax2 = ANCH[a][2] + sx;
  float ay2 = ANCH[a][3] + sy;
  float aw = ax2 - ax1 + 1.0f;
  float ah = ay2 - ay1 + 1.0f;
  float acx = ax1 + 0.5f * aw;
  float acy = ay1 + 0.5f * ah;
  int base = h * FW + w;
  float d0 = deltas[(4*a+0)*HW + base];
  float d1 = deltas[(4*a+1)*HW + base];
  float d2 = deltas[(4*a+2)*HW + base];
  float d3 = deltas[(4*a+3)*HW + base];
  float pcx = d0 * aw + acx;
  float pcy = d1 * ah + acy;
  float pw = expf(d2) * aw;
  float ph = expf(d3) * ah;
  x1 = pcx - 0.5f * pw;
  y1 = pcy - 0.5f * ph;
  x2 = pcx + 0.5f * pw;
  y2 = pcy + 0.5f * ph;
  x1 = fminf(fmaxf(x1, 0.0f), im_w - 1.0f);
  x2 = fminf(fmaxf(x2, 0.0f), im_w - 1.0f);
  y1 = fminf(fmaxf(y1, 0.0f), im_h - 1.0f);
  y2 = fminf(fmaxf(y2, 0.0f), im_h - 1.0f);
}

__device__ __forceinline__ u64 rl64(u64 v, int l) {
  unsigned lo = (unsigned)__builtin_amdgcn_readlane((int)(unsigned)(v & 0xFFFFFFFFull), l);
  unsigned hi = (unsigned)__builtin_amdgcn_readlane((int)(unsigned)(v >> 32), l);
  return ((u64)hi << 32) | lo;
}

// ---------------- cooperative mega-kernel: everything except final NMS -------------
__global__ void __launch_bounds__(NTHR, 2) k_mega(
    const float* __restrict__ scores, const float* __restrict__ deltas,
    const float* __restrict__ im_info, unsigned* __restrict__ keys,
    unsigned* __restrict__ hist8, unsigned* __restrict__ hist15,
    unsigned* __restrict__ scal, u64* __restrict__ remvI,
    u64* __restrict__ cand, unsigned* __restrict__ rankArr,
    float4* __restrict__ boxes, float* __restrict__ scoresArr,
    u64* __restrict__ mask) {
  cooperative_groups::grid_group gg = cooperative_groups::this_grid();
  __shared__ u64 smem[2048];               // 16 KB, phase-unioned
  __shared__ unsigned svar[4];
  unsigned* sh32 = (unsigned*)smem;
  int t = threadIdx.x, b = blockIdx.x;
  int gtid = b * NTHR + t;

  // ---- P0: init (replaces memsets) ----
  if (gtid < 256)       hist8[gtid] = 0;
  if (gtid < 32768)     hist15[gtid] = 0;
  if (gtid < 64)        scal[gtid] = 0;
  if (gtid < 192)       remvI[gtid] = ~0ULL;       // default: suppressed
  if (gtid < CAND_MAX)  rankArr[gtid] = 0;
  gg.sync();

  // ---- P1: decode + keys + hist8 ----
  {
    sh32[t] = 0;
    __syncthreads();
    float im_h = im_info[0], im_w = im_info[1];
    float ms = MIN_SIZE_C * im_info[2];
    for (int rep = 0; rep < 2; rep++) {
      int base = gtid + rep * GSIZE;       // < HW
      int h = base >> 9, w = base & 511;
      for (int a = 0; a < NA; a++) {
        float x1, y1, x2, y2;
        decode_box(a, h, w, deltas, im_h, im_w, x1, y1, x2, y2);
        bool valid = ((x2 - x1 + 1.0f) >= ms) && ((y2 - y1 + 1.0f) >= ms);
        float sc = scores[(NA + a)*HW + base];
        float v = valid ? sc : -INFINITY;
        unsigned u = __float_as_uint(v);
        unsigned mono = (u & 0x80000000u) ? ~u : (u | 0x80000000u);
        keys[a*HW + base] = mono;          // anchor-major: coalesced
        atomicAdd(&sh32[mono >> 24], 1u);
      }
    }
    __syncthreads();
    atomicAdd(&hist8[t], sh32[t]);
  }
  gg.sync();

  // ---- P2: find8 (per block) + 15-bit refine histogram ----
  {
    unsigned hv = hist8[t];
    sh32[t] = hv;
    __syncthreads();
    for (int off = 1; off < 256; off <<= 1) {
      unsigned v = sh32[t];
      unsigned add = (t + off < 256) ? sh32[t + off] : 0u;
      __syncthreads();
      sh32[t] = v + add;
      __syncthreads();
    }
    unsigned above = sh32[t] - hv;
    if (above < PRE_NMS && above + hv >= PRE_NMS) svar[0] = (unsigned)t;
    __syncthreads();
    unsigned B8 = svar[0];
    for (int i = gtid; i < TOTAL; i += GSIZE) {
      unsigned k = keys[i];
      if ((k >> 24) == B8) atomicAdd(&hist15[(k >> 9) & 0x7FFFu], 1u);
    }
  }
  gg.sync();

  // ---- P3: find8 + find15 -> threshold K; compact candidates ----
  {
    unsigned hv = hist8[t];
    __syncthreads();
    sh32[t] = hv;
    __syncthreads();
    for (int off = 1; off < 256; off <<= 1) {
      unsigned v = sh32[t];
      unsigned add = (t + off < 256) ? sh32[t + off] : 0u;
      __syncthreads();
      sh32[t] = v + add;
      __syncthreads();
    }
    unsigned above = sh32[t] - hv;
    if (above < PRE_NMS && above + hv >= PRE_NMS) { svar[0] = (unsigned)t; svar[1] = PRE_NMS - above; }
    __syncthreads();
    unsigned B8 = svar[0], T2 = svar[1];
    unsigned loc = 0;
    for (int i = 0; i < 128; i++) loc += hist15[t*128 + i];
    __syncthreads();
    sh32[t] = loc;
    __syncthreads();
    for (int off = 1; off < 256; off <<= 1) {
      unsigned v = sh32[t];
      unsigned add = (t + off < 256) ? sh32[t + off] : 0u;
      __syncthreads();
      sh32[t] = v + add;
      __syncthreads();
    }
    unsigned above15 = sh32[t] - loc;
    unsigned acc = above15;
    for (int i = 127; i >= 0; i--) {
      unsigned cb = hist15[t*128 + i];
      acc += cb;
      if (acc >= T2 && acc - cb < T2) svar[2] = (unsigned)(t*128 + i);
    }
    __syncthreads();
    unsigned K = (B8 << 24) | (svar[2] << 9);
    for (int i = gtid; i < TOTAL; i += GSIZE) {
      unsigned k = keys[i];
      if (k >= K) {
        unsigned pos = atomicAdd(&scal[4], 1u);
        if (pos < CAND_MAX) {
          unsigned a = ((unsigned)i) >> 18;         // /HW
          unsigned base2 = ((unsigned)i) & 262143u; // %HW
          unsigned oi = base2 * 9u + a;             // original flat index
          cand[pos] = ((u64)k << 32) | (unsigned)(~oi);
        }
      }
    }
  }
  gg.sync();

  // ---- P4a: partial ranks (64 i-groups x 8 j-octants = 512 units) ----
  {
    unsigned cnt = scal[4]; if (cnt > CAND_MAX) cnt = CAND_MAX;
    int ig = b >> 3, oc = b & 7;
    unsigned jn = (cnt + 7) >> 3;
    unsigned j0 = oc * jn;
    unsigned j1 = j0 + jn; if (j1 > cnt) j1 = cnt;
    if (j0 > cnt) j0 = cnt;
    for (unsigned j = j0 + t; j < j1; j += NTHR) smem[j - j0] = cand[j];
    __syncthreads();
    int i = ig * NTHR + t;
    if (i < (int)cnt && j1 > j0) {
      u64 mine = cand[i];
      int n = (int)(j1 - j0);
      int q0 = 0, q1 = 0, q2 = 0, q3 = 0, j = 0;
      for (; j + 4 <= n; j += 4) {
        q0 += (smem[j]   > mine) ? 1 : 0;
        q1 += (smem[j+1] > mine) ? 1 : 0;
        q2 += (smem[j+2] > mine) ? 1 : 0;
        q3 += (smem[j+3] > mine) ? 1 : 0;
      }
      for (; j < n; j++) q0 += (smem[j] > mine) ? 1 : 0;
      int part = q0 + q1 + q2 + q3;
      if (part) atomicAdd(&rankArr[i], (unsigned)part);
    }
  }
  gg.sync();

  // ---- P4b: decode top-12000 into boxes/scores; clear remv bit for valid ----
  {
    unsigned cnt = scal[4]; if (cnt > CAND_MAX) cnt = CAND_MAX;
    if (gtid < (int)cnt) {
      u64 mine = cand[gtid];
      unsigned rank = rankArr[gtid];
      if (rank < PRE_NMS) {
        unsigned mono = (unsigned)(mine >> 32);
        unsigned idx = ~(unsigned)(mine & 0xFFFFFFFFull);
        unsigned u = (mono & 0x80000000u) ? (mono ^ 0x80000000u) : ~mono;
        float sc = __uint_as_float(u);
        int a = idx % NA;
        int base = idx / NA;
        int h = base / FW, w = base % FW;
        float x1, y1, x2, y2;
        decode_box(a, h, w, deltas, im_info[0], im_info[1], x1, y1, x2, y2);
        boxes[rank] = make_float4(x1, y1, x2, y2);
        scoresArr[rank] = sc;
        if (sc > -INFINITY)
          atomicAnd(&remvI[rank >> 6], ~(1ULL << (rank & 63)));
      }
    }
  }
  gg.sync();

  // ---- P5: suppression mask, row-major [row][word], upper triangle only ----
  {
    float4* jb = (float4*)smem;              // 512 boxes = 8 KB
    for (int u = b; u < 24 * 47; u += NBLK) {
      int wg = u % 24;                       // word group: words [wg*8, wg*8+8)
      int bg = u / 24;                       // row group: rows [bg*256, bg*256+256)
      if (wg * 8 + 7 < bg * 4) continue;     // uniform per block: safe
      __syncthreads();
      for (int q = t; q < 512; q += NTHR) {
        int jg = wg * 512 + q;
        jb[q] = (jg < PRE_NMS) ? boxes[jg] : make_float4(0.f, 0.f, -1.f, -1.f);
      }
      __syncthreads();
      int i = bg * 256 + t;
      if (i < PRE_NMS && wg * 8 + 7 >= (i >> 6)) {
        float4 bx = boxes[i];
        float area_i = (bx.z - bx.x + 1.0f) * (bx.w - bx.y + 1.0f);
        u64 bits[8];
        #pragma unroll
        for (int k = 0; k < 8; k++) {
          u64 bb = 0;
          for (int jj = 0; jj < 64; jj++) {
            float4 o = jb[k * 64 + jj];
            float xx1 = fmaxf(bx.x, o.x);
            float yy1 = fmaxf(bx.y, o.y);
            float xx2 = fminf(bx.z, o.z);
            float yy2 = fminf(bx.w, o.w);
            float iw = fmaxf(xx2 - xx1 + 1.0f, 0.0f);
            float ih = fmaxf(yy2 - yy1 + 1.0f, 0.0f);
            float inter = iw * ih;
            float area_o = (o.z - o.x + 1.0f) * (o.w - o.y + 1.0f);
            float iou = inter / (area_i + area_o - inter);
            if (iou > NMS_TH) bb |= (1ULL << jj);
          }
          bits[k] = bb;
        }
        size_t rb = (size_t)i * MROW + wg * 8;
        #pragma unroll
        for (int k = 0; k < 8; k++) mask[rb + k] = bits[k];
      }
    }
  }
}

// ---------------- single-wave greedy NMS, depth-2 pipeline, readlane resolve -------
// State R (words 0..191) distributed: lane l owns words l, 64+l, 128+l.
// Keep j in chunk c: word c+1 contribution folded into resolve via readlane(nw1,j);
// full row DMA'd to LDS stage, ORed into R next iteration. diag/nw1 for chunk c+2
// issued at END of iter c -> everything vmcnt(0) waits on is >= 1 iteration old.
__global__ void __launch_bounds__(64) k_nms(const u64* __restrict__ mask,
    const u64* __restrict__ remvI,
    const float4* __restrict__ boxes, const float* __restrict__ scoresArr,
    float* __restrict__ out) {
  extern __shared__ u64 dyn[];
  u64* stage = dyn;                              // 64 rows x 192 words = 96 KiB
  unsigned* klist = (unsigned*)(dyn + 64 * MROW);
  int lane = threadIdx.x;                        // 64
  u64 r0 = remvI[lane];
  u64 r1 = remvI[64 + lane];
  u64 r2 = remvI[128 + lane];
  u64 W = rl64(r0, 0);                           // W_0
  // prologue: preload diag/nw1 for chunks 0 and 1
  u64 diagc = mask[(size_t)lane * MROW + 0];
  u64 nw1c  = mask[(size_t)lane * MROW + 1];
  u64 diagn = mask[(size_t)(64 + lane) * MROW + 1];
  u64 nw1n  = mask[(size_t)(64 + lane) * MROW + 2];
  int kept_cnt = 0, nkPrev = 0;
  bool done = false;
  for (int c = 0; c < NMS_WORDS; c++) {
    // 1. serial resolve of chunk c (wave-uniform, scalar-friendly readlane)
    int gi0 = c * 64;
    int jmax = PRE_NMS - gi0; if (jmax > 64) jmax = 64;
    u64 avail = ~W;
    if (jmax < 64) avail &= ((1ULL << jmax) - 1ULL);
    u64 keptmask = 0, A = 0;
    while (avail) {
      int j = __ffsll((long long)avail) - 1;
      keptmask |= (1ULL << j);
      if (lane == 0) klist[kept_cnt] = (unsigned)(gi0 + j);
      kept_cnt++;
      if (kept_cnt >= POST_NMS) { done = true; break; }
      u64 supp = rl64(diagc, j);                 // row (gi0+j)'s word c (self-bit set)
      A |= rl64(nw1c, j);                        // row (gi0+j)'s word c+1
      avail &= ~supp;
      avail &= ~((2ULL << j) - 1ULL);            // clear bits <= j
    }
    if (done || c + 1 >= NMS_WORDS) break;
    // 2. drain: stage DMAs (chunk c-1 keeps) + diag/nw1 preloads for chunk c+1 —
    //    all issued >= one full iteration ago.
    asm volatile("s_waitcnt vmcnt(0)" ::: "memory");
    __builtin_amdgcn_sched_barrier(0);
    // 3. OR staged rows (chunk c-1 keeps) into distributed R
    for (int s = 0; s < nkPrev; s++) {
      r0 |= stage[(size_t)s * MROW + lane];
      r1 |= stage[(size_t)s * MROW + 64 + lane];
      r2 |= stage[(size_t)s * MROW + 128 + lane];
    }
    // 4. W_{c+1} = R[c+1] | A
    int cw = c + 1;
    u64 Rw = (cw < 64) ? r0 : ((cw < 128) ? r1 : r2);
    W = rl64(Rw, cw & 63) | A;
    // 5. issue stage DMAs for chunk-c keeps (whole rows, coalesced, no VGPR cost)
    int slot = 0;
    u64 km = keptmask;
    while (km) {
      int j = __ffsll((long long)km) - 1; km &= km - 1;
      const char* rb = (const char*)(mask + (size_t)(gi0 + j) * MROW);
      char* lb = (char*)(void*)stage + slot * 1536;
      __builtin_amdgcn_global_load_lds(
          (const __attribute__((address_space(1))) unsigned*)(rb + lane * 16),
          (__attribute__((address_space(3))) unsigned*)lb, 16, 0, 0);
      if (lane < 32)
        __builtin_amdgcn_global_load_lds(
            (const __attribute__((address_space(1))) unsigned*)(rb + 1024 + lane * 16),
            (__attribute__((address_space(3))) unsigned*)(lb + 1024), 16, 0, 0);
      slot++;
    }
    nkPrev = slot;
    // 6. issue diag/nw1 preloads for chunk c+2 (consumed after NEXT drain)
    u64 d2 = 0, n2 = 0;
    if (c + 2 < NMS_WORDS) {
      size_t rb = (size_t)((c + 2) * 64 + lane) * MROW;
      d2 = mask[rb + (c + 2)];
      if (c + 3 < NMS_WORDS) n2 = mask[rb + (c + 3)];
    }
    diagc = diagn; nw1c = nw1n; diagn = d2; nw1n = n2;
  }
  __syncthreads();
  // epilogue: rois + scores, zero-filled past kept_cnt
  for (int s = lane; s < POST_NMS; s += 64) {
    float x1 = 0.f, y1 = 0.f, x2 = 0.f, y2 = 0.f, sc = 0.f;
    if (s < kept_cnt) {
      unsigned r = klist[s];
      float4 b = boxes[r];
      x1 = b.x; y1 = b.y; x2 = b.z; y2 = b.w;
      sc = scoresArr[r];
    }
    out[s*5 + 0] = 0.f;
    out[s*5 + 1] = x1;
    out[s*5 + 2] = y1;
    out[s*5 + 3] = x2;
    out[s*5 + 4] = y2;
    out[POST_NMS*5 + s] = sc;
  }
}

extern "C" void kernel_launch(void* const* d_in, const int* in_sizes, int n_in,
                              void* d_out, int out_size, void* d_ws, size_t ws_size,
                              hipStream_t stream) {
  const float* scores  = (const float*)d_in[0];
  const float* deltas  = (const float*)d_in[1];
  const float* im_info = (const float*)d_in[2];
  float* out = (float*)d_out;
  char* ws = (char*)d_ws;

  // workspace layout (bytes)
  unsigned* keys    = (unsigned*)(ws + 0);            //  9,437,184
  unsigned* hist8   = (unsigned*)(ws + 9437184);      //  1,024
  unsigned* hist15  = (unsigned*)(ws + 9438208);      //  131,072
  unsigned* scal    = (unsigned*)(ws + 9569280);      //  256
  u64* remvI        = (u64*)(ws + 9569536);           //  1,536 (192 words)
  u64* cand         = (u64*)(ws + 9571072);           //  131,072
  unsigned* rankArr = (unsigned*)(ws + 9702144);      //  65,536
  float4* boxes     = (float4*)(ws + 9767680);        //  192,512 (12032 entries)
  float* scoresArr  = (float*)(ws + 9960192);         //  48,128
  u64* mask         = (u64*)(ws + 10008576);          //  12032*1536 = 18,481,152 -> ~28.5 MB

  void* args[] = { (void*)&scores, (void*)&deltas, (void*)&im_info, (void*)&keys,
                   (void*)&hist8, (void*)&hist15, (void*)&scal, (void*)&remvI,
                   (void*)&cand, (void*)&rankArr, (void*)&boxes, (void*)&scoresArr,
                   (void*)&mask };
  hipLaunchCooperativeKernel((void*)k_mega, dim3(NBLK), dim3(NTHR), args, 0, stream);

  (void)hipFuncSetAttribute((const void*)k_nms,
        hipFuncAttributeMaxDynamicSharedMemorySize, 64*MROW*8 + POST_NMS*4);
  k_nms<<<1, 64, 64*MROW*8 + POST_NMS*4, stream>>>(mask, remvI, boxes, scoresArr, out);
}

// Round 6
// 853.173 us; speedup vs baseline: 1.2475x; 1.2475x over previous
//
#include <hip/hip_runtime.h>
#include <hip/hip_bf16.h>
#include <stdint.h>

#pragma clang fp contract(off)

typedef unsigned long long u64;

#define FH 512
#define FW 512
#define NA 9
#define HW (FH*FW)
#define TOTAL (HW*NA)
#define PRE_NMS 12000
#define POST_NMS 2000
#define NMS_WORDS 188            // ceil(12000/64)
#define MROW 192                 // padded words per mask row (1536 B)
#define CAND_MAX 16384
#define NMS_TH 0.7f
#define MIN_SIZE_C 16.0f

// generate_anchors(16, (0.5,1,2), (8,16,32)) — classic py-faster-rcnn table
__constant__ float ANCH[NA][4] = {
  {-84.f,-40.f,99.f,55.f},
  {-176.f,-88.f,191.f,103.f},
  {-360.f,-184.f,375.f,199.f},
  {-56.f,-56.f,71.f,71.f},
  {-120.f,-120.f,135.f,135.f},
  {-248.f,-248.f,263.f,263.f},
  {-36.f,-80.f,51.f,95.f},
  {-80.f,-168.f,95.f,183.f},
  {-168.f,-344.f,183.f,359.f}
};

__device__ __forceinline__ void decode_box(int a, int h, int w,
    const float* __restrict__ deltas, float im_h, float im_w,
    float& x1, float& y1, float& x2, float& y2) {
  float sx = (float)(w * 16);
  float sy = (float)(h * 16);
  float ax1 = ANCH[a][0] + sx;
  float ay1 = ANCH[a][1] + sy;
  float ax2 = ANCH[a][2] + sx;
  float ay2 = ANCH[a][3] + sy;
  float aw = ax2 - ax1 + 1.0f;
  float ah = ay2 - ay1 + 1.0f;
  float acx = ax1 + 0.5f * aw;
  float acy = ay1 + 0.5f * ah;
  int base = h * FW + w;
  float d0 = deltas[(4*a+0)*HW + base];
  float d1 = deltas[(4*a+1)*HW + base];
  float d2 = deltas[(4*a+2)*HW + base];
  float d3 = deltas[(4*a+3)*HW + base];
  float pcx = d0 * aw + acx;
  float pcy = d1 * ah + acy;
  float pw = expf(d2) * aw;
  float ph = expf(d3) * ah;
  x1 = pcx - 0.5f * pw;
  y1 = pcy - 0.5f * ph;
  x2 = pcx + 0.5f * pw;
  y2 = pcy + 0.5f * ph;
  x1 = fminf(fmaxf(x1, 0.0f), im_w - 1.0f);
  x2 = fminf(fmaxf(x2, 0.0f), im_w - 1.0f);
  y1 = fminf(fmaxf(y1, 0.0f), im_h - 1.0f);
  y2 = fminf(fmaxf(y2, 0.0f), im_h - 1.0f);
}

__device__ __forceinline__ u64 rl64(u64 v, int l) {
  unsigned lo = (unsigned)__builtin_amdgcn_readlane((int)(unsigned)(v & 0xFFFFFFFFull), l);
  unsigned hi = (unsigned)__builtin_amdgcn_readlane((int)(unsigned)(v >> 32), l);
  return ((u64)hi << 32) | lo;
}

// ---- K1: decode + keys (anchor-major, coalesced) + 8-bit top-byte histogram ----
__global__ void k_keys(const float* __restrict__ scores, const float* __restrict__ deltas,
                       const float* __restrict__ im_info, unsigned* __restrict__ keys,
                       unsigned* __restrict__ hist8) {
  __shared__ unsigned lh[256];
  int t = threadIdx.x;
  lh[t] = 0;
  __syncthreads();
  int base = blockIdx.x * blockDim.x + t;     // < HW
  float im_h = im_info[0], im_w = im_info[1];
  float ms = MIN_SIZE_C * im_info[2];
  int h = base >> 9, w = base & 511;
  for (int a = 0; a < NA; a++) {
    float x1, y1, x2, y2;
    decode_box(a, h, w, deltas, im_h, im_w, x1, y1, x2, y2);
    bool valid = ((x2 - x1 + 1.0f) >= ms) && ((y2 - y1 + 1.0f) >= ms);
    float sc = scores[(NA + a)*HW + base];
    float v = valid ? sc : -INFINITY;
    unsigned u = __float_as_uint(v);
    unsigned mono = (u & 0x80000000u) ? ~u : (u | 0x80000000u);
    keys[a*HW + base] = mono;
    atomicAdd(&lh[mono >> 24], 1u);
  }
  __syncthreads();
  atomicAdd(&hist8[t], lh[t]);
}

// ---- K2: per-block find8 -> B8; histogram bits[23:9] of matching keys -> hist15 ----
__global__ void __launch_bounds__(256) k_refine15(const unsigned* __restrict__ keys,
    const unsigned* __restrict__ hist8, unsigned* __restrict__ hist15) {
  __shared__ unsigned ssum[256];
  __shared__ unsigned sB8;
  int t = threadIdx.x;
  unsigned hv = hist8[t];
  ssum[t] = hv;
  __syncthreads();
  for (int off = 1; off < 256; off <<= 1) {
    unsigned v = ssum[t];
    unsigned add = (t + off < 256) ? ssum[t + off] : 0u;
    __syncthreads();
    ssum[t] = v + add;
    __syncthreads();
  }
  unsigned above = ssum[t] - hv;
  if (above < PRE_NMS && above + hv >= PRE_NMS) sB8 = (unsigned)t;
  __syncthreads();
  unsigned B8 = sB8;
  int stride = gridDim.x * blockDim.x;
  for (int i = blockIdx.x * blockDim.x + t; i < TOTAL; i += stride) {
    unsigned k = keys[i];
    if ((k >> 24) == B8) atomicAdd(&hist15[(k >> 9) & 0x7FFFu], 1u);
  }
}

// ---- K3: find8+find15 -> threshold K; compact (keys >= K), cnt <= ~12010 ----
__global__ void __launch_bounds__(256) k_compact(const unsigned* __restrict__ keys,
    const unsigned* __restrict__ hist8, const unsigned* __restrict__ hist15,
    unsigned* __restrict__ cnt, u64* __restrict__ cand) {
  __shared__ unsigned ssum[256];
  __shared__ unsigned sB8, sT2, sB15;
  int t = threadIdx.x;
  unsigned hv = hist8[t];
  ssum[t] = hv;
  __syncthreads();
  for (int off = 1; off < 256; off <<= 1) {
    unsigned v = ssum[t];
    unsigned add = (t + off < 256) ? ssum[t + off] : 0u;
    __syncthreads();
    ssum[t] = v + add;
    __syncthreads();
  }
  unsigned above = ssum[t] - hv;
  if (above < PRE_NMS && above + hv >= PRE_NMS) { sB8 = (unsigned)t; sT2 = PRE_NMS - above; }
  __syncthreads();
  unsigned B8 = sB8, T2 = sT2;
  unsigned loc = 0;
  for (int i = 0; i < 128; i++) loc += hist15[t*128 + i];
  __syncthreads();
  ssum[t] = loc;
  __syncthreads();
  for (int off = 1; off < 256; off <<= 1) {
    unsigned v = ssum[t];
    unsigned add = (t + off < 256) ? ssum[t + off] : 0u;
    __syncthreads();
    ssum[t] = v + add;
    __syncthreads();
  }
  unsigned above15 = ssum[t] - loc;
  unsigned acc = above15;
  for (int i = 127; i >= 0; i--) {
    unsigned cb = hist15[t*128 + i];
    acc += cb;
    if (acc >= T2 && acc - cb < T2) sB15 = (unsigned)(t*128 + i);
  }
  __syncthreads();
  unsigned K = (B8 << 24) | (sB15 << 9);
  int stride = gridDim.x * blockDim.x;
  for (int i = blockIdx.x * blockDim.x + t; i < TOTAL; i += stride) {
    unsigned k = keys[i];
    if (k >= K) {
      unsigned pos = atomicAdd(cnt, 1u);
      if (pos < CAND_MAX) {
        unsigned a = ((unsigned)i) >> 18;          // key idx is a*HW+base
        unsigned base2 = ((unsigned)i) & 262143u;
        unsigned oi = base2 * 9u + a;              // original flat (h,w,a) index
        cand[pos] = ((u64)k << 32) | (unsigned)(~oi);
      }
    }
  }
}

// ---- K4: exact rank (O(N^2), j-split over 4 wave-groups) + decode fused ----
// 64 blocks x 1024 threads: thread owns i = b*256 + (t&255), scans j-quarter (t>>8).
__global__ void __launch_bounds__(1024) k_rankdec(const unsigned* __restrict__ pcnt,
    const u64* __restrict__ cand,
    const float* __restrict__ deltas, const float* __restrict__ im_info,
    float4* __restrict__ boxes, float* __restrict__ scoresArr,
    u64* __restrict__ remvI) {
  __shared__ u64 tile[2048];
  __shared__ unsigned part[256][4];
  unsigned cnt = *pcnt;
  if (cnt > CAND_MAX) cnt = CAND_MAX;
  int t = threadIdx.x;
  int iq = t & 255, qw = t >> 8;
  int i = blockIdx.x * 256 + iq;
  u64 mine = (i < (int)cnt) ? cand[i] : ~0ULL;
  unsigned pr = 0;
  for (unsigned t0 = 0; t0 < cnt; t0 += 2048) {
    unsigned n = min(2048u, cnt - t0);
    __syncthreads();
    for (unsigned j = t; j < n; j += 1024) tile[j] = cand[t0 + j];
    __syncthreads();
    if (i < (int)cnt) {
      unsigned j0 = qw * 512;
      unsigned j1 = min(j0 + 512, n);
      for (unsigned j = j0; j < j1; j++) pr += (tile[j] > mine) ? 1u : 0u;
    }
  }
  part[iq][qw] = pr;
  __syncthreads();
  if (t < 256 && (blockIdx.x * 256 + t) < (int)cnt) {
    unsigned rank = part[t][0] + part[t][1] + part[t][2] + part[t][3];
    if (rank < PRE_NMS) {
      u64 m = cand[blockIdx.x * 256 + t];
      unsigned mono = (unsigned)(m >> 32);
      unsigned idx = ~(unsigned)(m & 0xFFFFFFFFull);
      unsigned u = (mono & 0x80000000u) ? (mono ^ 0x80000000u) : ~mono;
      float sc = __uint_as_float(u);
      int a = idx % NA;
      int base = idx / NA;
      int h = base / FW, w = base % FW;
      float x1, y1, x2, y2;
      decode_box(a, h, w, deltas, im_info[0], im_info[1], x1, y1, x2, y2);
      boxes[rank] = make_float4(x1, y1, x2, y2);
      scoresArr[rank] = sc;
      if (sc > -INFINITY)
        atomicAnd(&remvI[rank >> 6], ~(1ULL << (rank & 63)));
    }
  }
}

// ---- K5: suppression mask, row-major [row][word], upper triangle (+straddle) ----
// block (wg, bg): rows [bg*256, +256) x words [wg*8, +8); thread stores 64 contiguous B.
__global__ void __launch_bounds__(256) k_mask(const float4* __restrict__ boxes,
                                              u64* __restrict__ mask) {
  int wg = blockIdx.x;   // [0,24)
  int bg = blockIdx.y;   // [0,47)
  if (wg * 8 + 7 < bg * 4) return;
  __shared__ float4 jb[512];
  int t = threadIdx.x;
  for (int q = t; q < 512; q += 256) {
    int jg = wg * 512 + q;
    jb[q] = (jg < PRE_NMS) ? boxes[jg] : make_float4(0.f, 0.f, -1.f, -1.f);
  }
  __syncthreads();
  int i = bg * 256 + t;
  if (i >= PRE_NMS || wg * 8 + 7 < (i >> 6)) return;
  float4 b = boxes[i];
  float area_i = (b.z - b.x + 1.0f) * (b.w - b.y + 1.0f);
  u64 bits[8];
  #pragma unroll
  for (int k = 0; k < 8; k++) {
    u64 bb = 0;
    for (int jj = 0; jj < 64; jj++) {
      float4 o = jb[k * 64 + jj];
      float xx1 = fmaxf(b.x, o.x);
      float yy1 = fmaxf(b.y, o.y);
      float xx2 = fminf(b.z, o.z);
      float yy2 = fminf(b.w, o.w);
      float iw = fmaxf(xx2 - xx1 + 1.0f, 0.0f);
      float ih = fmaxf(yy2 - yy1 + 1.0f, 0.0f);
      float inter = iw * ih;
      float area_o = (o.z - o.x + 1.0f) * (o.w - o.y + 1.0f);
      float iou = inter / (area_i + area_o - inter);
      if (iou > NMS_TH) bb |= (1ULL << jj);
    }
    bits[k] = bb;
  }
  size_t rb = (size_t)i * MROW + wg * 8;
  #pragma unroll
  for (int k = 0; k < 8; k++) mask[rb + k] = bits[k];
}

// ---- K6: 8-wave producer/worker greedy NMS ----
// Wave 0: serial resolve only. R[192] (future-word OR state) lives in LDS,
// maintained by waves 1-7, lagging ONE chunk; wave0's register A covers the lag
// (chunk-c keeps' word c+1 via readlane of preloaded nw1). One barrier per chunk.
__global__ void __launch_bounds__(512) k_nms(const u64* __restrict__ mask,
    const u64* __restrict__ remvI,
    const float4* __restrict__ boxes, const float* __restrict__ scoresArr,
    float* __restrict__ out) {
  __shared__ unsigned R32[384];          // R[192] as 2x u32
  __shared__ unsigned klist[POST_NMS];
  __shared__ int sPub[2][2];             // [c&1][{start,end}]
  __shared__ int sDone, sKept;
  int t = threadIdx.x;
  int lane = t & 63, wv = t >> 6;
  for (int w = t; w < 384; w += 512) R32[w] = ((const unsigned*)remvI)[w];
  if (t == 0) { sDone = 0; sPub[0][0] = sPub[0][1] = sPub[1][0] = sPub[1][1] = 0; }
  __syncthreads();
  u64 diag0 = 0, nw10 = 0, diag1 = 0, nw11 = 0, A = 0;
  int kept = 0;
  if (wv == 0) {
    diag0 = mask[(size_t)lane * MROW + 0];
    nw10  = mask[(size_t)lane * MROW + 1];
    diag1 = mask[(size_t)(64 + lane) * MROW + 1];
    nw11  = mask[(size_t)(64 + lane) * MROW + 2];
  }
  for (int c = 0; c < NMS_WORDS; c++) {
    if (wv == 0) {
      // resolve chunk c
      int gi0 = c * 64;
      int jmax = PRE_NMS - gi0; if (jmax > 64) jmax = 64;
      u64 Rc = ((u64)R32[2*c + 1] << 32) | R32[2*c];
      u64 avail = ~(Rc | A);
      if (jmax < 64) avail &= ((1ULL << jmax) - 1ULL);
      A = 0;
      int st = kept;
      bool done = false;
      while (avail) {
        int j = __ffsll((long long)avail) - 1;
        if (lane == 0) klist[kept] = (unsigned)(gi0 + j);
        kept++;
        if (kept >= POST_NMS) { done = true; break; }
        u64 supp = rl64(diag0, j);     // row (gi0+j) word c (self-bit set)
        A |= rl64(nw10, j);            // row (gi0+j) word c+1
        avail &= ~supp;
        avail &= ~((2ULL << j) - 1ULL);
      }
      if (lane == 0) {
        sPub[c & 1][0] = st; sPub[c & 1][1] = kept;
        if (done || c == NMS_WORDS - 1) sDone = 1;
      }
      // preload diag/nw1 for chunk c+2 (consumed 2 windows later)
      u64 d2 = 0, n2 = 0;
      if (c + 2 < NMS_WORDS) {
        size_t rb = (size_t)((c + 2) * 64 + lane) * MROW;
        d2 = mask[rb + (c + 2)];
        if (c + 3 < NMS_WORDS) n2 = mask[rb + (c + 3)];
      }
      diag0 = diag1; nw10 = nw11; diag1 = d2; nw11 = n2;
    } else if (c > 0) {
      // workers: OR rows of chunk-(c-1) keeps into R (covers chunks <= c-1 by c+1)
      int s0 = sPub[(c - 1) & 1][0], s1 = sPub[(c - 1) & 1][1];
      u64 o0 = 0, o1 = 0, o2 = 0;
      bool any = false;
      for (int q = s0 + (wv - 1); q < s1; q += 7) {
        const u64* rp = mask + (size_t)klist[q] * MROW;
        o0 |= rp[lane];
        o1 |= rp[64 + lane];
        o2 |= rp[128 + lane];
        any = true;
      }
      if (any) {
        atomicOr(&R32[2*lane],             (unsigned)o0);
        atomicOr(&R32[2*lane + 1],         (unsigned)(o0 >> 32));
        atomicOr(&R32[2*(64 + lane)],      (unsigned)o1);
        atomicOr(&R32[2*(64 + lane) + 1],  (unsigned)(o1 >> 32));
        atomicOr(&R32[2*(128 + lane)],     (unsigned)o2);
        atomicOr(&R32[2*(128 + lane) + 1], (unsigned)(o2 >> 32));
      }
    }
    __syncthreads();
    if (sDone) break;
  }
  if (t == 0) sKept = kept;
  __syncthreads();
  int kc = sKept;
  for (int s = t; s < POST_NMS; s += 512) {
    float x1 = 0.f, y1 = 0.f, x2 = 0.f, y2 = 0.f, sc = 0.f;
    if (s < kc) {
      unsigned r = klist[s];
      float4 b = boxes[r];
      x1 = b.x; y1 = b.y; x2 = b.z; y2 = b.w;
      sc = scoresArr[r];
    }
    out[s*5 + 0] = 0.f;
    out[s*5 + 1] = x1;
    out[s*5 + 2] = y1;
    out[s*5 + 3] = x2;
    out[s*5 + 4] = y2;
    out[POST_NMS*5 + s] = sc;
  }
}

extern "C" void kernel_launch(void* const* d_in, const int* in_sizes, int n_in,
                              void* d_out, int out_size, void* d_ws, size_t ws_size,
                              hipStream_t stream) {
  const float* scores  = (const float*)d_in[0];
  const float* deltas  = (const float*)d_in[1];
  const float* im_info = (const float*)d_in[2];
  float* out = (float*)d_out;
  char* ws = (char*)d_ws;

  // workspace layout (bytes)
  unsigned* keys    = (unsigned*)(ws + 0);            //  9,437,184
  unsigned* hist8   = (unsigned*)(ws + 9437184);      //  1,024
  unsigned* hist15  = (unsigned*)(ws + 9438208);      //  131,072
  unsigned* scal    = (unsigned*)(ws + 9569280);      //  256
  u64* remvI        = (u64*)(ws + 9569536);           //  1,536 (192 words)
  u64* cand         = (u64*)(ws + 9571072);           //  131,072
  float4* boxes     = (float4*)(ws + 9767680);        //  192,512 (12032 entries)
  float* scoresArr  = (float*)(ws + 9960192);         //  48,128
  u64* mask         = (u64*)(ws + 10008576);          //  12032 rows x 1536 B = 18,481,152

  hipMemsetAsync(ws + 9437184, 0, 132352, stream);     // hist8+hist15+scal
  hipMemsetAsync(ws + 9569536, 0xFF, 1536, stream);    // remvI: default-suppressed

  k_keys<<<HW/256, 256, 0, stream>>>(scores, deltas, im_info, keys, hist8);
  k_refine15<<<512, 256, 0, stream>>>(keys, hist8, hist15);
  k_compact<<<512, 256, 0, stream>>>(keys, hist8, hist15, &scal[4], cand);
  k_rankdec<<<CAND_MAX/256, 1024, 0, stream>>>(&scal[4], cand, deltas, im_info,
                                               boxes, scoresArr, remvI);
  dim3 mg(24, 47);
  k_mask<<<mg, 256, 0, stream>>>(boxes, mask);
  k_nms<<<1, 512, 0, stream>>>(mask, remvI, boxes, scoresArr, out);
}